// Round 1
// baseline (70.242 us; speedup 1.0000x reference)
//
#include <hip/hip_runtime.h>
#include <math.h>

// Problem constants (from reference): B=32, H=100, C=50, D=400, HID=400
#define B_   32
#define H_   100
#define C_   50
#define D_   400
#define HID_ 400
#define NTHREADS 512
#define NWAVES (NTHREADS / 64)

// Key identity: scores[b,c,h] = cand_term[b,c] + hist[b,h]·u + const, where
// u[d] = sum_j W1[D+d][j] * w2[j]. Softmax over h cancels everything except
// hist[b,h]·u (masked entries are the constant finfo.min -> weight 0, or
// uniform if ALL masked — both reproduced by expf(s-max) with s=-FLT_MAX).
// Then out[b,c,:] = mask_cand[b,c] ? sum_h w[b,h]*hist[b,h,:] : 0.

__global__ __launch_bounds__(NTHREADS)
void user_encoder_fused(const float* __restrict__ hist,       // (B,H,D)
                        const int*   __restrict__ mask_hist,  // (B,H) 0/1
                        const int*   __restrict__ mask_cand,  // (B,C) 0/1
                        const float* __restrict__ W1,         // (2D,HID) row-major
                        const float* __restrict__ w2,         // (HID)
                        float* __restrict__ out)               // (B,C,D)
{
    __shared__ float u_lds[D_];
    __shared__ float s_lds[H_];
    __shared__ float w_lds[H_];
    __shared__ float red[NWAVES];

    const int b    = blockIdx.x;
    const int tid  = threadIdx.x;
    const int lane = tid & 63;
    const int wave = tid >> 6;

    const float NEG = -3.4028234663852886e38f;  // finfo(f32).min

    // ---- Phase 1: u[d] = dot(W1[D+d, :], w2)  (one row per wave) ----
    for (int d = wave; d < D_; d += NWAVES) {
        const float* row = W1 + (size_t)(D_ + d) * HID_;
        float acc = 0.f;
        for (int j = lane; j < HID_; j += 64)
            acc = fmaf(row[j], w2[j], acc);
        for (int off = 32; off; off >>= 1)
            acc += __shfl_xor(acc, off, 64);
        if (lane == 0) u_lds[d] = acc;
    }
    __syncthreads();

    // ---- Phase 2: s[h] = mask ? dot(hist[b,h,:], u) : NEG ----
    const float* histb = hist + (size_t)b * H_ * D_;
    for (int h = wave; h < H_; h += NWAVES) {
        const float* row = histb + h * D_;
        float acc = 0.f;
        for (int j = lane; j < D_; j += 64)
            acc = fmaf(row[j], u_lds[j], acc);
        for (int off = 32; off; off >>= 1)
            acc += __shfl_xor(acc, off, 64);
        if (lane == 0)
            s_lds[h] = mask_hist[b * H_ + h] ? acc : NEG;
    }
    __syncthreads();

    // ---- Phase 3: softmax over s[0..H) ----
    // block max
    float m = -INFINITY;
    for (int h = tid; h < H_; h += NTHREADS) m = fmaxf(m, s_lds[h]);
    for (int off = 32; off; off >>= 1) m = fmaxf(m, __shfl_xor(m, off, 64));
    if (lane == 0) red[wave] = m;
    __syncthreads();
    m = red[0];
    #pragma unroll
    for (int i = 1; i < NWAVES; i++) m = fmaxf(m, red[i]);
    __syncthreads();   // everyone done reading red[] (max) before reuse

    // exp + block sum
    float psum = 0.f;
    for (int h = tid; h < H_; h += NTHREADS) {
        float e = expf(s_lds[h] - m);
        w_lds[h] = e;
        psum += e;
    }
    for (int off = 32; off; off >>= 1) psum += __shfl_xor(psum, off, 64);
    if (lane == 0) red[wave] = psum;
    __syncthreads();
    float sum = 0.f;
    #pragma unroll
    for (int i = 0; i < NWAVES; i++) sum += red[i];
    const float inv = 1.f / sum;
    for (int h = tid; h < H_; h += NTHREADS) w_lds[h] *= inv;
    __syncthreads();

    // ---- Phase 4: uv[d] = sum_h w[h] * hist[b,h,d]  (d = tid, coalesced) ----
    float uv = 0.f;
    if (tid < D_) {
        #pragma unroll 4
        for (int h = 0; h < H_; h++)
            uv = fmaf(w_lds[h], histb[h * D_ + tid], uv);
    }

    // ---- Phase 5: out[b,c,:] = mask_cand[b,c] ? uv : 0 ----
    const int* mcb   = mask_cand + b * C_;
    float*     outb  = out + (size_t)b * C_ * D_;
    if (tid < D_) {
        for (int c = 0; c < C_; c++)
            outb[c * D_ + tid] = mcb[c] ? uv : 0.f;
    }
}

extern "C" void kernel_launch(void* const* d_in, const int* in_sizes, int n_in,
                              void* d_out, int out_size, void* d_ws, size_t ws_size,
                              hipStream_t stream) {
    // setup_inputs order:
    // 0: hist_news_vector (B,H,D) f32
    // 1: cand_news_vector (B,C,D) f32   [unused — cancels in softmax]
    // 2: mask_hist (B,H) int
    // 3: mask_cand (B,C) int
    // 4: W1 (2D,HID) f32   [only rows D..2D-1 matter]
    // 5: b1 (HID,) f32     [unused — cancels]
    // 6: w2 (HID,) f32
    // 7: b2 () f32         [unused — cancels]
    const float* hist      = (const float*)d_in[0];
    const int*   mask_hist = (const int*)d_in[2];
    const int*   mask_cand = (const int*)d_in[3];
    const float* W1        = (const float*)d_in[4];
    const float* w2        = (const float*)d_in[6];
    float* out = (float*)d_out;

    user_encoder_fused<<<B_, NTHREADS, 0, stream>>>(hist, mask_hist, mask_cand, W1, w2, out);
}

// Round 2
// 17.053 us; speedup vs baseline: 4.1191x; 4.1191x over previous
//
#include <hip/hip_runtime.h>
#include <math.h>

// Problem constants: B=32, H=100, C=50, D=400, HID=400
#define B_   32
#define H_   100
#define C_   50
#define D_   400
#define HID_ 400

#define NEGF (-3.4028234663852886e38f)  // finfo(float32).min

// Algebraic collapse (verified R1, absmax 1.5e-5):
//   scores[b,c,h] = cand_term[b,c] + hist[b,h]·u + const,  u = W1[D:,:] @ w2
//   softmax over h cancels cand_term and const; mask -> s = finfo.min.
//   out[b,c,:] = mask_cand[b,c] ? sum_h softmax(s[b,:])[h] * hist[b,h,:] : 0
//
// R1 showed 32-block fused kernel is latency-starved (VALUBusy 0.8%, occ 2.9%).
// Split into 3 kernels with proper grids; u and s staged in d_ws.

// ---- K1: u[d] = dot(W1[D+d,:], w2), one wave per row. grid=50, block=512 ----
__global__ __launch_bounds__(512)
void k1_u(const float* __restrict__ W1, const float* __restrict__ w2,
          float* __restrict__ u) {
    const int row  = blockIdx.x * 8 + (threadIdx.x >> 6);   // 0..399
    const int lane = threadIdx.x & 63;
    const float* wrow = W1 + (size_t)(D_ + row) * HID_;
    float acc = 0.f;
    #pragma unroll
    for (int j = lane; j < HID_; j += 64)
        acc = fmaf(wrow[j], w2[j], acc);
    #pragma unroll
    for (int off = 32; off; off >>= 1)
        acc += __shfl_xor(acc, off, 64);
    if (lane == 0) u[row] = acc;
}

// ---- K2: s[b*H+h] = mask ? hist[b,h]·u : NEG, one wave per row.
//      grid=400, block=512 (3200 rows) ----
__global__ __launch_bounds__(512)
void k2_s(const float* __restrict__ hist, const int* __restrict__ mask_hist,
          const float* __restrict__ u, float* __restrict__ s) {
    const int row  = blockIdx.x * 8 + (threadIdx.x >> 6);   // 0..3199 = b*100+h
    const int lane = threadIdx.x & 63;
    const float* hrow = hist + (size_t)row * D_;
    float acc = 0.f;
    #pragma unroll
    for (int j = lane; j < D_; j += 64)
        acc = fmaf(hrow[j], u[j], acc);
    #pragma unroll
    for (int off = 32; off; off >>= 1)
        acc += __shfl_xor(acc, off, 64);
    if (lane == 0) s[row] = mask_hist[row] ? acc : NEGF;
}

// ---- K3: per (b, d-tile of 64): redundant softmax over s[b,:], h split
//      across 4 waves for uv, LDS reduce, masked broadcast store of 50 c's.
//      grid = 32*7 = 224, block=256 ----
#define NTILES 7   // ceil(400/64)

__global__ __launch_bounds__(256)
void k3_out(const float* __restrict__ hist, const float* __restrict__ s,
            const int* __restrict__ mask_cand, float* __restrict__ out) {
    __shared__ float w_lds[128];       // weights, h=0..99 used
    __shared__ float part[4][64];
    __shared__ float uv_lds[64];

    const int b    = blockIdx.x / NTILES;
    const int tile = blockIdx.x % NTILES;
    const int d0   = tile * 64;
    const int lane = threadIdx.x & 63;
    const int wave = threadIdx.x >> 6;
    const int d    = d0 + lane;        // may be >= 400 on last tile

    // --- softmax over s[b, 0..99], computed redundantly per wave ---
    const float* sb = s + b * H_;
    const float s0 = sb[lane];                                   // h = lane (<100)
    const float s1 = (lane + 64 < H_) ? sb[lane + 64] : -INFINITY;
    float m = fmaxf(s0, s1);
    #pragma unroll
    for (int off = 32; off; off >>= 1)
        m = fmaxf(m, __shfl_xor(m, off, 64));
    const float e0 = expf(s0 - m);
    const float e1 = (lane + 64 < H_) ? expf(s1 - m) : 0.f;
    float ps = e0 + e1;
    #pragma unroll
    for (int off = 32; off; off >>= 1)
        ps += __shfl_xor(ps, off, 64);
    const float inv = 1.f / ps;

    if (wave == 0) {
        w_lds[lane] = e0 * inv;
        if (lane + 64 < H_) w_lds[lane + 64] = e1 * inv;
    }
    __syncthreads();

    // --- uv[d] partials: wave w handles h in [w*25, w*25+25) ---
    const float* hb = hist + (size_t)b * H_ * D_;
    float acc = 0.f;
    if (d < D_) {
        const int h0 = wave * 25;
        #pragma unroll
        for (int i = 0; i < 25; i++)
            acc = fmaf(w_lds[h0 + i], hb[(h0 + i) * D_ + d], acc);
    }
    part[wave][lane] = acc;
    __syncthreads();
    if (wave == 0)
        uv_lds[lane] = part[0][lane] + part[1][lane] + part[2][lane] + part[3][lane];
    __syncthreads();

    // --- broadcast store: out[b,c,d0+lane] for c = wave, wave+4, ... ---
    const float uv = uv_lds[lane];
    const int* mcb = mask_cand + b * C_;
    float* outb = out + (size_t)b * C_ * D_ + d0;
    if (d < D_) {
        for (int c = wave; c < C_; c += 4)
            outb[(size_t)c * D_ + lane] = mcb[c] ? uv : 0.f;
    }
}

extern "C" void kernel_launch(void* const* d_in, const int* in_sizes, int n_in,
                              void* d_out, int out_size, void* d_ws, size_t ws_size,
                              hipStream_t stream) {
    // inputs: 0 hist(B,H,D) f32, 1 cand [unused], 2 mask_hist(B,H) i32,
    //         3 mask_cand(B,C) i32, 4 W1(2D,HID) f32, 5 b1 [unused],
    //         6 w2(HID) f32, 7 b2 [unused]
    const float* hist      = (const float*)d_in[0];
    const int*   mask_hist = (const int*)d_in[2];
    const int*   mask_cand = (const int*)d_in[3];
    const float* W1        = (const float*)d_in[4];
    const float* w2        = (const float*)d_in[6];
    float* out = (float*)d_out;

    float* u = (float*)d_ws;           // 400 floats
    float* s = u + D_;                 // 3200 floats  (total 14.4 KB < ws_size)

    k1_u  <<<D_ / 8,        512, 0, stream>>>(W1, w2, u);
    k2_s  <<<(B_ * H_) / 8, 512, 0, stream>>>(hist, mask_hist, u, s);
    k3_out<<<B_ * NTILES,   256, 0, stream>>>(hist, s, mask_cand, out);
}